// Round 3
// baseline (975.747 us; speedup 1.0000x reference)
//
#include <hip/hip_runtime.h>

#define NN   100000
#define NE   3200000
#define DIMK 512
#define HIDN 16
#define NCLS 64
#define NSEG 1024
#define SEGLEN 98          // ceil(100000/1024)

// ---- threefry2x32-20, JAX partitionable path (default in modern JAX) ----
// 32-bit random_bits: counts = iota(u64); (b1,b2) = threefry2x32(key, hi, lo);
// bits32 = b1 ^ b2.  Here hi=0, lo=i, key=(0,42).
__device__ __forceinline__ unsigned rotl32(unsigned x, int r){ return (x << r) | (x >> (32 - r)); }

__device__ __forceinline__ unsigned threefry_bits(unsigned i){
  const unsigned k0 = 0u, k1 = 42u;
  const unsigned k2 = 0x1BD11BDAu ^ k0 ^ k1;
  unsigned a = 0u + k0, b = i + k1;
#define TF_R(r) { a += b; b = rotl32(b, (r)); b ^= a; }
  TF_R(13) TF_R(15) TF_R(26) TF_R(6)  a += k1; b += k2 + 1u;
  TF_R(17) TF_R(29) TF_R(16) TF_R(24) a += k2; b += k0 + 2u;
  TF_R(13) TF_R(15) TF_R(26) TF_R(6)  a += k0; b += k1 + 3u;
  TF_R(17) TF_R(29) TF_R(16) TF_R(24) a += k1; b += k2 + 4u;
  TF_R(13) TF_R(15) TF_R(26) TF_R(6)  a += k2; b += k0 + 5u;
#undef TF_R
  return a ^ b;   // keep iff !(bits & 0x80000000)
}

// ---------------- degree count / norm ----------------
__global__ void k_count(const int* __restrict__ col, int* __restrict__ cnt){
  int e = blockIdx.x * blockDim.x + threadIdx.x;
  if (e < NE) atomicAdd(&cnt[col[e]], 1);
}

__global__ void k_dis(const int* __restrict__ cnt, float* __restrict__ dis){
  int n = blockIdx.x * blockDim.x + threadIdx.x;
  if (n < NN) dis[n] = rsqrtf((float)(cnt[n] + 1));   // +1 self-loop; deg >= 1 always
}

// ---------------- CSR build: segment sums -> scan -> offsets -> fill ----------------
__global__ void k_segsum(const int* __restrict__ cnt, int* __restrict__ tsum){
  int t = blockIdx.x * blockDim.x + threadIdx.x;   // 0..1023
  int s = 0;
  int start = t * SEGLEN;
  int end = start + SEGLEN; if (end > NN) end = NN;
  for (int i = start; i < end; ++i) s += cnt[i];
  tsum[t] = s;
}

__global__ void k_scan(const int* __restrict__ tsum, int* __restrict__ toff){
  __shared__ int s[NSEG];
  int t = threadIdx.x;
  s[t] = tsum[t];
  __syncthreads();
  for (int off = 1; off < NSEG; off <<= 1){
    int v = (t >= off) ? s[t - off] : 0;
    __syncthreads();
    s[t] += v;
    __syncthreads();
  }
  toff[t] = s[t] - tsum[t];   // exclusive
}

__global__ void k_fill_offs(const int* __restrict__ cnt, const int* __restrict__ toff,
                            int* __restrict__ offs){
  int t = blockIdx.x * blockDim.x + threadIdx.x;
  int run = toff[t];
  int start = t * SEGLEN;
  int end = start + SEGLEN; if (end > NN) end = NN;
  for (int i = start; i < end; ++i){ offs[i] = run; run += cnt[i]; }
}

__global__ void k_fill_csr(const int* __restrict__ row, const int* __restrict__ col,
                           int* __restrict__ cursor, int* __restrict__ csr){
  int e = blockIdx.x * blockDim.x + threadIdx.x;
  if (e < NE){
    int d = col[e];
    int p = atomicAdd(&cursor[d], 1);
    csr[p] = row[e];
  }
}

// ---------------- h1 = x @ W1  (wave per node, W1 in registers, fold-reduce) ----------------
__global__ __launch_bounds__(256) void k_gemm1(const float* __restrict__ x,
                                               const float* __restrict__ W1,
                                               float* __restrict__ h1){
  const int lane = threadIdx.x & 63;
  const int wid  = (blockIdx.x * blockDim.x + threadIdx.x) >> 6;
  const int nw   = (gridDim.x * blockDim.x) >> 6;
  const bool s5 = (lane & 32) != 0;
  const bool s4 = (lane & 16) != 0;
  const bool s3 = (lane & 8)  != 0;
  const bool s2 = (lane & 4)  != 0;

  // lane holds W1 rows [lane*8, lane*8+8), all 16 cols -> 128 VGPRs
  float4 w4[8][4];
  const float4* W1v = (const float4*)W1;
#pragma unroll
  for (int k = 0; k < 8; ++k)
#pragma unroll
    for (int jj = 0; jj < 4; ++jj)
      w4[k][jj] = W1v[(lane * 8 + k) * 4 + jj];

  for (int n = wid; n < NN; n += nw){
    const float4* xp = (const float4*)(x + (size_t)n * DIMK + lane * 8);
    float4 xa = xp[0], xb = xp[1];
    float xv[8] = {xa.x, xa.y, xa.z, xa.w, xb.x, xb.y, xb.z, xb.w};
    float acc[16];
#pragma unroll
    for (int j = 0; j < 16; ++j) acc[j] = 0.f;
#pragma unroll
    for (int k = 0; k < 8; ++k){
      float xk = xv[k];
#pragma unroll
      for (int jj = 0; jj < 4; ++jj){
        acc[jj*4+0] = fmaf(xk, w4[k][jj].x, acc[jj*4+0]);
        acc[jj*4+1] = fmaf(xk, w4[k][jj].y, acc[jj*4+1]);
        acc[jj*4+2] = fmaf(xk, w4[k][jj].z, acc[jj*4+2]);
        acc[jj*4+3] = fmaf(xk, w4[k][jj].w, acc[jj*4+3]);
      }
    }
    // value-folding reduction: 16 partials x 64 lanes -> lane L holds h[(L>>2)&15]
    float t8[8];
#pragma unroll
    for (int m = 0; m < 8; ++m){
      float keep = s5 ? acc[8+m] : acc[m];
      float give = s5 ? acc[m]   : acc[8+m];
      t8[m] = keep + __shfl_xor(give, 32, 64);
    }
    float t4[4];
#pragma unroll
    for (int m = 0; m < 4; ++m){
      float keep = s4 ? t8[4+m] : t8[m];
      float give = s4 ? t8[m]   : t8[4+m];
      t4[m] = keep + __shfl_xor(give, 16, 64);
    }
    float t2[2];
#pragma unroll
    for (int m = 0; m < 2; ++m){
      float keep = s3 ? t4[2+m] : t4[m];
      float give = s3 ? t4[m]   : t4[2+m];
      t2[m] = keep + __shfl_xor(give, 8, 64);
    }
    float keep = s2 ? t2[1] : t2[0];
    float give = s2 ? t2[0] : t2[1];
    float v = keep + __shfl_xor(give, 4, 64);
    v += __shfl_xor(v, 2, 64);
    v += __shfl_xor(v, 1, 64);
    // gather h[j] to lane j (j<16), coalesced 64B store
    float hv = __shfl(v, (lane & 15) * 4, 64);
    if (lane < 16) h1[(size_t)n * HIDN + lane] = hv;
  }
}

// ---------------- layer-1 aggregation + bias + relu + dropout ----------------
__global__ void k_agg1(const float* __restrict__ h1, const float* __restrict__ dis,
                       const int* __restrict__ offs, const int* __restrict__ cnt,
                       const int* __restrict__ csr, const float* __restrict__ b1,
                       float* __restrict__ h2){
  int tid = blockIdx.x * blockDim.x + threadIdx.x;
  int n = tid >> 4, j = tid & 15;
  if (n >= NN) return;
  float dn = dis[n];
  float acc = h1[n * HIDN + j] * dn * dn;            // self-loop
  int s = offs[n], e = s + cnt[n];
  for (int idx = s; idx < e; ++idx){
    int src = csr[idx];
    acc = fmaf(h1[src * HIDN + j], dis[src] * dn, acc);
  }
  float v = fmaxf(acc + b1[j], 0.f);
  unsigned bits = threefry_bits((unsigned)(n * HIDN + j));
  h2[n * HIDN + j] = (bits & 0x80000000u) ? 0.f : v * 2.f;   // /(1-p) = *2
}

// ---------------- layer-2 aggregation (pre-GEMM, by linearity) ----------------
__global__ void k_agg2(const float* __restrict__ h2, const float* __restrict__ dis,
                       const int* __restrict__ offs, const int* __restrict__ cnt,
                       const int* __restrict__ csr, float* __restrict__ agg){
  int tid = blockIdx.x * blockDim.x + threadIdx.x;
  int n = tid >> 4, j = tid & 15;
  if (n >= NN) return;
  float dn = dis[n];
  float acc = h2[n * HIDN + j] * dn * dn;
  int s = offs[n], e = s + cnt[n];
  for (int idx = s; idx < e; ++idx){
    int src = csr[idx];
    acc = fmaf(h2[src * HIDN + j], dis[src] * dn, acc);
  }
  agg[n * HIDN + j] = acc;
}

// ---------------- logits = agg @ W2 + b2, then log_softmax (wave per node) ----------------
__global__ void k_out(const float* __restrict__ agg, const float* __restrict__ W2,
                      const float* __restrict__ b2, float* __restrict__ out){
  const int lane = threadIdx.x & 63;
  const int wid  = (blockIdx.x * blockDim.x + threadIdx.x) >> 6;
  const int nw   = (gridDim.x * blockDim.x) >> 6;
  float wc[16];
#pragma unroll
  for (int k = 0; k < 16; ++k) wc[k] = W2[k * NCLS + lane];
  float bb = b2[lane];
  for (int n = wid; n < NN; n += nw){
    const float4* av = (const float4*)(agg + (size_t)n * HIDN);
    float4 a0 = av[0], a1 = av[1], a2 = av[2], a3 = av[3];
    float v = bb;
    v = fmaf(a0.x, wc[0],  v); v = fmaf(a0.y, wc[1],  v);
    v = fmaf(a0.z, wc[2],  v); v = fmaf(a0.w, wc[3],  v);
    v = fmaf(a1.x, wc[4],  v); v = fmaf(a1.y, wc[5],  v);
    v = fmaf(a1.z, wc[6],  v); v = fmaf(a1.w, wc[7],  v);
    v = fmaf(a2.x, wc[8],  v); v = fmaf(a2.y, wc[9],  v);
    v = fmaf(a2.z, wc[10], v); v = fmaf(a2.w, wc[11], v);
    v = fmaf(a3.x, wc[12], v); v = fmaf(a3.y, wc[13], v);
    v = fmaf(a3.z, wc[14], v); v = fmaf(a3.w, wc[15], v);
    float m = v;
#pragma unroll
    for (int d = 32; d; d >>= 1) m = fmaxf(m, __shfl_xor(m, d, 64));
    float ex = __expf(v - m);
    float sum = ex;
#pragma unroll
    for (int d = 32; d; d >>= 1) sum += __shfl_xor(sum, d, 64);
    out[(size_t)n * NCLS + lane] = (v - m) - __logf(sum);
  }
}

// ---------------- launch ----------------
extern "C" void kernel_launch(void* const* d_in, const int* in_sizes, int n_in,
                              void* d_out, int out_size, void* d_ws, size_t ws_size,
                              hipStream_t stream){
  const float* x  = (const float*)d_in[0];
  const int*   ei = (const int*)  d_in[1];
  const float* W1 = (const float*)d_in[2];
  const float* b1 = (const float*)d_in[3];
  const float* W2 = (const float*)d_in[4];
  const float* b2 = (const float*)d_in[5];
  float* out = (float*)d_out;
  const int* row = ei;          // sources
  const int* col = ei + NE;     // destinations

  char* ws = (char*)d_ws;
  int*   degcnt = (int*)  (ws + 0);         // 400000 B
  float* dis    = (float*)(ws + 400000);    // 400000 B
  int*   offs   = (int*)  (ws + 800000);    // 400000 B
  int*   cursor = (int*)  (ws + 1200000);   // 400000 B
  int*   tsum   = (int*)  (ws + 1600000);   // 4096 B
  int*   toff   = (int*)  (ws + 1604096);   // 4096 B
  int*   csr    = (int*)  (ws + 1608192);   // 12.8 MB
  float* h1     = (float*)(ws + 14408192);  // 6.4 MB
  float* h2     = (float*)(ws + 20808192);  // 6.4 MB
  float* agg2   = h1;                        // h1 dead after k_agg1 -> reuse

  hipMemsetAsync(degcnt, 0, NN * sizeof(int), stream);
  k_count    <<<(NE + 255) / 256, 256, 0, stream>>>(col, degcnt);
  k_dis      <<<(NN + 255) / 256, 256, 0, stream>>>(degcnt, dis);
  k_segsum   <<<4, 256, 0, stream>>>(degcnt, tsum);
  k_scan     <<<1, NSEG, 0, stream>>>(tsum, toff);
  k_fill_offs<<<4, 256, 0, stream>>>(degcnt, toff, offs);
  hipMemcpyAsync(cursor, offs, NN * sizeof(int), hipMemcpyDeviceToDevice, stream);
  k_fill_csr <<<(NE + 255) / 256, 256, 0, stream>>>(row, col, cursor, csr);
  k_gemm1    <<<1024, 256, 0, stream>>>(x, W1, h1);
  k_agg1     <<<(NN * HIDN + 255) / 256, 256, 0, stream>>>(h1, dis, offs, degcnt, csr, b1, h2);
  k_agg2     <<<(NN * HIDN + 255) / 256, 256, 0, stream>>>(h2, dis, offs, degcnt, csr, agg2);
  k_out      <<<2048, 256, 0, stream>>>(agg2, W2, b2, out);
}

// Round 4
// 824.322 us; speedup vs baseline: 1.1837x; 1.1837x over previous
//
#include <hip/hip_runtime.h>

#define NN   100000
#define NE   3200000
#define DIMK 512
#define HIDN 16
#define NCLS 64

// ---- threefry2x32-20, JAX partitionable 32-bit path: bits = x0_final ^ x1_final,
// key=(0,42), counter=(0, i). Verified R3 (absmax 0.031).
__device__ __forceinline__ unsigned rotl32(unsigned x, int r){ return (x << r) | (x >> (32 - r)); }

__device__ __forceinline__ unsigned threefry_bits(unsigned i){
  const unsigned k0 = 0u, k1 = 42u;
  const unsigned k2 = 0x1BD11BDAu ^ k0 ^ k1;
  unsigned a = 0u + k0, b = i + k1;
#define TF_R(r) { a += b; b = rotl32(b, (r)); b ^= a; }
  TF_R(13) TF_R(15) TF_R(26) TF_R(6)  a += k1; b += k2 + 1u;
  TF_R(17) TF_R(29) TF_R(16) TF_R(24) a += k2; b += k0 + 2u;
  TF_R(13) TF_R(15) TF_R(26) TF_R(6)  a += k0; b += k1 + 3u;
  TF_R(17) TF_R(29) TF_R(16) TF_R(24) a += k1; b += k2 + 4u;
  TF_R(13) TF_R(15) TF_R(26) TF_R(6)  a += k2; b += k0 + 5u;
#undef TF_R
  return a ^ b;   // keep iff !(bits & 0x80000000)
}

// ---------------- degree count / norm ----------------
__global__ void k_count(const int* __restrict__ col, int* __restrict__ cnt){
  int e = blockIdx.x * blockDim.x + threadIdx.x;
  if (e < NE) atomicAdd(&cnt[col[e]], 1);
}

__global__ void k_dis(const int* __restrict__ cnt, float* __restrict__ dis){
  int n = blockIdx.x * blockDim.x + threadIdx.x;
  if (n < NN) dis[n] = rsqrtf((float)(cnt[n] + 1));   // +1 self-loop; deg >= 1 always
}

// ---- h1 = x @ W1, epilogue pre-scales by dis[n]: hs = h1 * dis[n] ----
__global__ __launch_bounds__(256) void k_gemm1(const float* __restrict__ x,
                                               const float* __restrict__ W1,
                                               const float* __restrict__ dis,
                                               float* __restrict__ hs){
  const int lane = threadIdx.x & 63;
  const int wid  = (blockIdx.x * blockDim.x + threadIdx.x) >> 6;
  const int nw   = (gridDim.x * blockDim.x) >> 6;
  const bool s5 = (lane & 32) != 0;
  const bool s4 = (lane & 16) != 0;
  const bool s3 = (lane & 8)  != 0;
  const bool s2 = (lane & 4)  != 0;

  // lane holds W1 rows [lane*8, lane*8+8), all 16 cols -> 128 VGPRs
  float4 w4[8][4];
  const float4* W1v = (const float4*)W1;
#pragma unroll
  for (int k = 0; k < 8; ++k)
#pragma unroll
    for (int jj = 0; jj < 4; ++jj)
      w4[k][jj] = W1v[(lane * 8 + k) * 4 + jj];

  for (int n = wid; n < NN; n += nw){
    const float4* xp = (const float4*)(x + (size_t)n * DIMK + lane * 8);
    float4 xa = xp[0], xb = xp[1];
    float xv[8] = {xa.x, xa.y, xa.z, xa.w, xb.x, xb.y, xb.z, xb.w};
    float acc[16];
#pragma unroll
    for (int j = 0; j < 16; ++j) acc[j] = 0.f;
#pragma unroll
    for (int k = 0; k < 8; ++k){
      float xk = xv[k];
#pragma unroll
      for (int jj = 0; jj < 4; ++jj){
        acc[jj*4+0] = fmaf(xk, w4[k][jj].x, acc[jj*4+0]);
        acc[jj*4+1] = fmaf(xk, w4[k][jj].y, acc[jj*4+1]);
        acc[jj*4+2] = fmaf(xk, w4[k][jj].z, acc[jj*4+2]);
        acc[jj*4+3] = fmaf(xk, w4[k][jj].w, acc[jj*4+3]);
      }
    }
    // value-folding reduction: 16 partials x 64 lanes
    float t8[8];
#pragma unroll
    for (int m = 0; m < 8; ++m){
      float keep = s5 ? acc[8+m] : acc[m];
      float give = s5 ? acc[m]   : acc[8+m];
      t8[m] = keep + __shfl_xor(give, 32, 64);
    }
    float t4[4];
#pragma unroll
    for (int m = 0; m < 4; ++m){
      float keep = s4 ? t8[4+m] : t8[m];
      float give = s4 ? t8[m]   : t8[4+m];
      t4[m] = keep + __shfl_xor(give, 16, 64);
    }
    float t2[2];
#pragma unroll
    for (int m = 0; m < 2; ++m){
      float keep = s3 ? t4[2+m] : t4[m];
      float give = s3 ? t4[m]   : t4[2+m];
      t2[m] = keep + __shfl_xor(give, 8, 64);
    }
    float keep = s2 ? t2[1] : t2[0];
    float give = s2 ? t2[0] : t2[1];
    float v = keep + __shfl_xor(give, 4, 64);
    v += __shfl_xor(v, 2, 64);
    v += __shfl_xor(v, 1, 64);
    float hv = __shfl(v, (lane & 15) * 4, 64);
    if (lane < 16) hs[(size_t)n * HIDN + lane] = hv * dis[n];
  }
}

// ---- push-mode aggregation: scat[c*16+j] += src[r*16+j] (pre-scaled src) ----
__global__ __launch_bounds__(256) void k_scat(const int* __restrict__ row,
                                              const int* __restrict__ col,
                                              const float* __restrict__ src,
                                              float* __restrict__ scat){
  int t = blockIdx.x * blockDim.x + threadIdx.x;
  const int stride = gridDim.x * blockDim.x;   // multiple of 16
  const int j = t & 15;
  const int total = NE * HIDN;
  for (; t < total; t += stride){
    int e = t >> 4;
    int r = row[e];
    int c = col[e];
    atomicAdd(&scat[c * HIDN + j], src[r * HIDN + j]);   // fire-and-forget f32 atomic
  }
}

// ---- layer-1 finalize: dis*(scat+hs) + b1 -> relu -> dropout -> pre-scale for L2 ----
__global__ void k_fin1(const float* __restrict__ scat1, const float* __restrict__ hs,
                       const float* __restrict__ dis, const float* __restrict__ b1,
                       float* __restrict__ h2s){
  int t = blockIdx.x * blockDim.x + threadIdx.x;
  if (t >= NN * HIDN) return;
  int n = t >> 4, j = t & 15;
  float dn = dis[n];
  float v = fmaf(dn, scat1[t] + hs[t], b1[j]);
  v = fmaxf(v, 0.f);
  unsigned bits = threefry_bits((unsigned)t);
  float kept = (bits & 0x80000000u) ? 0.f : v * 2.f;   // /(1-p) = *2
  h2s[t] = kept * dn;                                   // pre-scale for layer-2 scatter
}

// ---- out: agg2 = dis*(scat2+h2s); logits = agg2@W2+b2; log_softmax (wave/node) ----
__global__ void k_out(const float* __restrict__ scat2, const float* __restrict__ h2s,
                      const float* __restrict__ dis, const float* __restrict__ W2,
                      const float* __restrict__ b2, float* __restrict__ out){
  const int lane = threadIdx.x & 63;
  const int wid  = (blockIdx.x * blockDim.x + threadIdx.x) >> 6;
  const int nw   = (gridDim.x * blockDim.x) >> 6;
  float wc[16];
#pragma unroll
  for (int k = 0; k < 16; ++k) wc[k] = W2[k * NCLS + lane];
  float bb = b2[lane];
  for (int n = wid; n < NN; n += nw){
    float dn = dis[n];
    const float4* sv = (const float4*)(scat2 + (size_t)n * HIDN);
    const float4* hv = (const float4*)(h2s   + (size_t)n * HIDN);
    float s = 0.f;
#pragma unroll
    for (int q = 0; q < 4; ++q){
      float4 a = sv[q], h = hv[q];
      s = fmaf(a.x + h.x, wc[q*4+0], s);
      s = fmaf(a.y + h.y, wc[q*4+1], s);
      s = fmaf(a.z + h.z, wc[q*4+2], s);
      s = fmaf(a.w + h.w, wc[q*4+3], s);
    }
    float v = fmaf(dn, s, bb);
    float m = v;
#pragma unroll
    for (int d = 32; d; d >>= 1) m = fmaxf(m, __shfl_xor(m, d, 64));
    float ex = __expf(v - m);
    float sum = ex;
#pragma unroll
    for (int d = 32; d; d >>= 1) sum += __shfl_xor(sum, d, 64);
    out[(size_t)n * NCLS + lane] = (v - m) - __logf(sum);
  }
}

// ---------------- launch ----------------
extern "C" void kernel_launch(void* const* d_in, const int* in_sizes, int n_in,
                              void* d_out, int out_size, void* d_ws, size_t ws_size,
                              hipStream_t stream){
  const float* x  = (const float*)d_in[0];
  const int*   ei = (const int*)  d_in[1];
  const float* W1 = (const float*)d_in[2];
  const float* b1 = (const float*)d_in[3];
  const float* W2 = (const float*)d_in[4];
  const float* b2 = (const float*)d_in[5];
  float* out = (float*)d_out;
  const int* row = ei;          // sources
  const int* col = ei + NE;     // destinations

  char* ws = (char*)d_ws;
  int*   degcnt = (int*)  (ws + 0);          // 400 KB
  float* dis    = (float*)(ws + 400000);     // 400 KB
  float* hs     = (float*)(ws + 800000);     // 6.4 MB  (h1 * dis)
  float* h2s    = (float*)(ws + 7200000);    // 6.4 MB  (dropout(relu(l1)) * dis)
  float* scat1  = (float*)(ws + 13600000);   // 6.4 MB  \ adjacent: one memset
  float* scat2  = (float*)(ws + 20000000);   // 6.4 MB  /

  hipMemsetAsync(degcnt, 0, NN * sizeof(int), stream);
  hipMemsetAsync(scat1, 0, 2 * NN * HIDN * sizeof(float), stream);  // scat1+scat2
  k_count <<<(NE + 255) / 256, 256, 0, stream>>>(col, degcnt);
  k_dis   <<<(NN + 255) / 256, 256, 0, stream>>>(degcnt, dis);
  k_gemm1 <<<1024, 256, 0, stream>>>(x, W1, dis, hs);
  k_scat  <<<8192, 256, 0, stream>>>(row, col, hs, scat1);
  k_fin1  <<<(NN * HIDN + 255) / 256, 256, 0, stream>>>(scat1, hs, dis, b1, h2s);
  k_scat  <<<8192, 256, 0, stream>>>(row, col, h2s, scat2);
  k_out   <<<2048, 256, 0, stream>>>(scat2, h2s, dis, W2, b2, out);
}